// Round 1
// baseline (148.182 us; speedup 1.0000x reference)
//
#include <hip/hip_runtime.h>

// Fused: h = emb[:, :256] @ W_enc + b_enc ; LayerNorm(h)*gamma+beta ; ReLU
// (topology branch of the reference is a provable no-op: pooled == embeddings)
//
// Shapes: emb [16384, 512] f32 (rows = B*S), W_enc [256, 512], out [16384, 512].

constexpr int D   = 512;
constexpr int DH  = 256;
constexpr int MT  = 16;     // rows per block
constexpr float EPS = 1e-5f;

__global__ __launch_bounds__(256)
void topo_fused(const float* __restrict__ emb,
                const float* __restrict__ Wenc,
                const float* __restrict__ benc,
                const float* __restrict__ gamma,
                const float* __restrict__ beta,
                float* __restrict__ out)
{
    __shared__ float A[MT][DH];   // 16 KB: A tile (first 256 cols of each row)
    __shared__ float H[MT][D];    // 32 KB: pre-LN activations

    const int t = threadIdx.x;               // 0..255
    const long row0 = (long)blockIdx.x * MT;

    // ---- Stage A tile: MT x DH floats, float4-vectorized, coalesced ----
    {
        const float4* src = (const float4*)emb;   // row stride D/4 = 128 float4
        #pragma unroll
        for (int j = 0; j < 4; ++j) {
            int idx = j * 256 + t;      // 0..1023 over MT*DH/4 float4s
            int r   = idx >> 6;         // 64 float4 per row
            int c4  = idx & 63;
            float4 v = src[(row0 + r) * (D / 4) + c4];
            *(float4*)&A[r][c4 * 4] = v;
        }
    }
    __syncthreads();

    // ---- Register-tiled GEMM: each thread = 16 rows x 2 adjacent cols ----
    const int c0 = 2 * t;                    // columns c0, c0+1
    float2 acc[MT];
    #pragma unroll
    for (int r = 0; r < MT; ++r) acc[r] = make_float2(0.f, 0.f);

    #pragma unroll 2
    for (int k0 = 0; k0 < DH; k0 += 4) {
        float2 w0 = *(const float2*)&Wenc[(k0 + 0) * D + c0];
        float2 w1 = *(const float2*)&Wenc[(k0 + 1) * D + c0];
        float2 w2 = *(const float2*)&Wenc[(k0 + 2) * D + c0];
        float2 w3 = *(const float2*)&Wenc[(k0 + 3) * D + c0];
        #pragma unroll
        for (int r = 0; r < MT; ++r) {
            float4 a = *(const float4*)&A[r][k0];   // LDS broadcast (conflict-free)
            acc[r].x = fmaf(a.x, w0.x, acc[r].x);
            acc[r].x = fmaf(a.y, w1.x, acc[r].x);
            acc[r].x = fmaf(a.z, w2.x, acc[r].x);
            acc[r].x = fmaf(a.w, w3.x, acc[r].x);
            acc[r].y = fmaf(a.x, w0.y, acc[r].y);
            acc[r].y = fmaf(a.y, w1.y, acc[r].y);
            acc[r].y = fmaf(a.z, w2.y, acc[r].y);
            acc[r].y = fmaf(a.w, w3.y, acc[r].y);
        }
    }

    // ---- + bias, park h in LDS for the row-wise LayerNorm ----
    const float bx = benc[c0], by = benc[c0 + 1];
    #pragma unroll
    for (int r = 0; r < MT; ++r) {
        float2 h = make_float2(acc[r].x + bx, acc[r].y + by);
        *(float2*)&H[r][c0] = h;
    }
    __syncthreads();

    // ---- LayerNorm + ReLU: each of 4 waves handles 4 rows ----
    const int lane = t & 63;
    const int wave = t >> 6;
    #pragma unroll
    for (int rr = 0; rr < MT / 4; ++rr) {
        const int r = wave * (MT / 4) + rr;
        float s = 0.f, ss = 0.f;
        #pragma unroll
        for (int j = 0; j < 8; ++j) {
            float v = H[r][lane + 64 * j];   // stride-64: conflict-free
            s += v;
            ss = fmaf(v, v, ss);
        }
        #pragma unroll
        for (int off = 32; off >= 1; off >>= 1) {
            s  += __shfl_xor(s,  off, 64);
            ss += __shfl_xor(ss, off, 64);
        }
        const float mu  = s * (1.f / 512.f);
        const float var = ss * (1.f / 512.f) - mu * mu;   // population var (ddof=0)
        const float inv = rsqrtf(var + EPS);
        float* orow = out + (row0 + r) * D;
        #pragma unroll
        for (int j = 0; j < 8; ++j) {
            int c = lane + 64 * j;
            float v = (H[r][c] - mu) * inv * gamma[c] + beta[c];
            orow[c] = fmaxf(v, 0.f);         // coalesced store
        }
    }
}

extern "C" void kernel_launch(void* const* d_in, const int* in_sizes, int n_in,
                              void* d_out, int out_size, void* d_ws, size_t ws_size,
                              hipStream_t stream) {
    // setup_inputs order: embeddings, W_proj, b_proj, W_enc, b_enc, ln_gamma, ln_beta
    const float* emb   = (const float*)d_in[0];
    // d_in[1] (W_proj), d_in[2] (b_proj) are provably unused (pooled == embeddings)
    const float* Wenc  = (const float*)d_in[3];
    const float* benc  = (const float*)d_in[4];
    const float* gamma = (const float*)d_in[5];
    const float* beta  = (const float*)d_in[6];
    float* out = (float*)d_out;

    const int rows = in_sizes[0] / D;        // B*S = 16384
    const int grid = rows / MT;              // 1024 blocks
    topo_fused<<<grid, 256, 0, stream>>>(emb, Wenc, benc, gamma, beta, out);
}